// Round 1
// baseline (7603.003 us; speedup 1.0000x reference)
//
#include <hip/hip_runtime.h>
#include <hip/hip_bf16.h>

#define T_STEPS 512
#define BATCH   128
#define HDIM    512
#define NBLK    128
#define FOUR_H  2048

typedef __attribute__((ext_vector_type(4))) float f32x4;
typedef __attribute__((ext_vector_type(8))) short s16x8;

// ---------- helpers ----------
__device__ __forceinline__ unsigned short f2bf(float f){
  unsigned int u = __float_as_uint(f);
  unsigned int r = (u + 0x7fffu + ((u >> 16) & 1u)) >> 16;
  return (unsigned short)r;
}
__device__ __forceinline__ float fsig(float x){
  return __builtin_amdgcn_rcpf(1.f + __expf(-x));
}
__device__ __forceinline__ float ftanh(float x){
  x = fminf(fmaxf(x, -15.f), 15.f);
  float a = __expf(2.f * x);
  return (a - 1.f) * __builtin_amdgcn_rcpf(a + 1.f);
}
// block p owns h-cols [p*4, p*4+4); its 16 z-cols, tile-index n in [0,16):
// gate g = n>>2, local col j = n&3  ->  global z col = g*512 + p*4 + j
__device__ __forceinline__ int colmap(int p, int n){
  return (n >> 2) * HDIM + p * 4 + (n & 3);
}

// ---------- pack x into MFMA A-fragment layout, bf16 ----------
// xp layout: [t][mt(8)][kt(16)][lane(64)][8]  (short)
__global__ void k_pack_x(const float* __restrict__ x, unsigned short* __restrict__ xp){
  int t = blockIdx.x;
  int lane = threadIdx.x & 63;
  int u0 = threadIdx.x >> 6;
  int rloc = lane & 15, koff = (lane >> 4) * 8;
  for (int u = u0; u < 128; u += 4){
    int mt = u >> 4, kt = u & 15;
    int row = mt * 16 + rloc;
    int k = kt * 32 + koff;
    const float* src = x + ((size_t)row * T_STEPS + t) * 512 + k;
    s16x8 v;
#pragma unroll
    for (int i = 0; i < 8; i++) v[i] = (short)f2bf(src[i]);
    ((s16x8*)xp)[(((size_t)t * 8 + mt) * 16 + kt) * 64 + lane] = v;
  }
}

// ---------- pack layer-1 weights [Wi1;Wh1] into B-fragment layout ----------
// wp layout: [p(128)][kt(32)][lane(64)][8]
__global__ void k_pack_w1(const float* __restrict__ Wi, const float* __restrict__ Wh,
                          const float* __restrict__ b, unsigned short* __restrict__ wp,
                          float* __restrict__ bias){
  int p = blockIdx.x;
  int lane = threadIdx.x & 63;
  int u0 = threadIdx.x >> 6;
  int koff = (lane >> 4) * 8;
  int col = colmap(p, lane & 15);
  for (int kt = u0; kt < 32; kt += 4){
    int kg = kt * 32 + koff;
    const float* W = (kt < 16) ? (Wi + (size_t)kg * FOUR_H + col)
                               : (Wh + (size_t)(kg - 512) * FOUR_H + col);
    s16x8 v;
#pragma unroll
    for (int i = 0; i < 8; i++) v[i] = (short)f2bf(W[(size_t)i * FOUR_H]);
    ((s16x8*)wp)[((size_t)p * 32 + kt) * 64 + lane] = v;
  }
  if (threadIdx.x < 16) bias[p * 16 + threadIdx.x] = b[colmap(p, threadIdx.x)];
}

// ---------- fold BN1 into Wi2 and pack layer-2 weights ----------
__global__ void k_fold2(const float* __restrict__ Wi2, const float* __restrict__ Wh2,
                        const float* __restrict__ b2, const float* __restrict__ gamma,
                        const float* __restrict__ beta, const float* __restrict__ stats,
                        unsigned short* __restrict__ wp, float* __restrict__ bias){
  __shared__ float a_s[512], c_s[512];
  __shared__ float red[256];
  int p = blockIdx.x, tid = threadIdx.x;
  for (int k = tid; k < 512; k += 256){
    float mean = stats[2*k] * (1.f/65536.f);
    float var  = stats[2*k+1] * (1.f/65536.f) - mean*mean;
    float r = rsqrtf(fmaxf(var, 0.f) + 1e-5f);
    float a = r * gamma[k];
    a_s[k] = a;
    c_s[k] = beta[k] - mean * a;
  }
  __syncthreads();
  int lane = tid & 63, u0 = tid >> 6;
  int koff = (lane >> 4) * 8;
  int col = colmap(p, lane & 15);
  for (int kt = u0; kt < 32; kt += 4){
    int kg = kt * 32 + koff;
    s16x8 v;
    if (kt < 16){
#pragma unroll
      for (int i = 0; i < 8; i++)
        v[i] = (short)f2bf(a_s[kg+i] * Wi2[(size_t)(kg+i)*FOUR_H + col]);
    } else {
#pragma unroll
      for (int i = 0; i < 8; i++)
        v[i] = (short)f2bf(Wh2[(size_t)(kg-512+i)*FOUR_H + col]);
    }
    ((s16x8*)wp)[((size_t)p * 32 + kt) * 64 + lane] = v;
  }
  // bias2 = b2 + c_s @ Wi2  (for this block's 16 cols)
  int n = tid >> 4, part = tid & 15;
  int bcol = colmap(p, n);
  float s = 0.f;
  for (int k = part*32; k < part*32 + 32; k++) s += c_s[k] * Wi2[(size_t)k*FOUR_H + bcol];
  red[tid] = s;
  __syncthreads();
  if (part == 0){
    float tot = b2[bcol];
#pragma unroll
    for (int q = 0; q < 16; q++) tot += red[n*16 + q];
    bias[p*16 + n] = tot;
  }
}

// ---------- reset sync flags ----------
__global__ void k_reset(int* f1, int* f2){
  int t = threadIdx.x;
  if (t < 128) f1[t] = 0;
  else if (t < 256) f2[t-128] = 0;
}

__global__ void k_sentinel(float* out, int n, float v){
  int i = blockIdx.x * blockDim.x + threadIdx.x;
  if (i < n) out[i] = v;
}

// ---------- persistent LSTM scan ----------
// 128 blocks x 512 threads. Block p owns h-cols [p*4,p*4+4).
// Per step: z[128 x 16cols] = [x_t | h_{t-1}] @ W  via mfma 16x16x32 bf16,
// A-frags read straight from packed global buffers, B-frags from LDS.
// h exchanged via hbuf[t] (fragment layout), flags = completed-step counters.
template<int LAYER>
__global__ __launch_bounds__(512)
void k_scan(const unsigned short* __restrict__ xsrc, const unsigned short* __restrict__ wp,
            const float* __restrict__ bias, unsigned short* __restrict__ hbuf,
            int* __restrict__ flags, float* __restrict__ aux){
  __shared__ unsigned short wlds[32*64*8];   // 32KB bf16 weights
  __shared__ float zlds[128*17];             // z bounce, padded
  __shared__ float blds[16];
  int p = blockIdx.x, tid = threadIdx.x;
  int wv = tid >> 6, lane = tid & 63;

  { const s16x8* src = (const s16x8*)wp + (size_t)p*32*64;
    s16x8* dst = (s16x8*)wlds;
    for (int j = tid; j < 32*64; j += 512) dst[j] = src[j]; }
  if (tid < 16) blds[tid] = bias[p*16 + tid];
  __syncthreads();

  int urow = tid & 127, uj = tid >> 7;       // update ownership: (row, local col)
  float c = 0.f, s1 = 0.f, s2 = 0.f;

  int rbase = wv*16 + ((lane>>4)<<2);
  int ncol = lane & 15;
  const s16x8* bw = (const s16x8*)wlds;

  for (int t = 0; t < T_STEPS; t++){
    f32x4 acc0 = {0.f,0.f,0.f,0.f}, acc1 = {0.f,0.f,0.f,0.f};
    // phase X: input projection part (no dependence on h_{t-1})
    const s16x8* ax = (const s16x8*)xsrc + (((size_t)t*8 + wv)*16)*64 + lane;
#pragma unroll
    for (int kt = 0; kt < 16; kt++){
      s16x8 a = ax[kt*64];
      s16x8 b = bw[kt*64 + lane];
      if (kt & 1) acc1 = __builtin_amdgcn_mfma_f32_16x16x32_bf16(a, b, acc1, 0, 0, 0);
      else        acc0 = __builtin_amdgcn_mfma_f32_16x16x32_bf16(a, b, acc0, 0, 0, 0);
    }
    // wait for all blocks to have produced h_{t-1}
    if (t > 0){
      if (tid < 64){
        int bail = 0;
        while (1){
          int f0 = __hip_atomic_load(&flags[lane],    __ATOMIC_RELAXED, __HIP_MEMORY_SCOPE_AGENT);
          int f1 = __hip_atomic_load(&flags[64+lane], __ATOMIC_RELAXED, __HIP_MEMORY_SCOPE_AGENT);
          if (__all(f0 >= t && f1 >= t)) break;
          __builtin_amdgcn_s_sleep(1);
          if (++bail > (1<<24)) break;   // safety: never hang the harness
        }
      }
      __syncthreads();
      const s16x8* ah = (const s16x8*)hbuf + (((size_t)(t-1)*8 + wv)*16)*64 + lane;
#pragma unroll
      for (int kt = 0; kt < 16; kt++){
        s16x8 a = ah[kt*64];
        s16x8 b = bw[(16+kt)*64 + lane];
        if (kt & 1) acc1 = __builtin_amdgcn_mfma_f32_16x16x32_bf16(a, b, acc1, 0, 0, 0);
        else        acc0 = __builtin_amdgcn_mfma_f32_16x16x32_bf16(a, b, acc0, 0, 0, 0);
      }
    }
    f32x4 z = acc0 + acc1;
#pragma unroll
    for (int i = 0; i < 4; i++) zlds[(rbase+i)*17 + ncol] = z[i];
    __syncthreads();

    // gate math: thread owns (urow, hcol = p*4+uj)
    float zi = zlds[urow*17 + uj]       + blds[uj];
    float zf = zlds[urow*17 + 4 + uj]   + blds[4+uj];
    float zg = zlds[urow*17 + 8 + uj]   + blds[8+uj];
    float zo = zlds[urow*17 + 12 + uj]  + blds[12+uj];
    float gi = fsig(zi), gf = fsig(zf), go = fsig(zo), gg = ftanh(zg);
    c = gf*c + gi*gg;
    float h = go * ftanh(c);
    if (LAYER == 1){ s1 += h; s2 += h*h; }
    // store h into fragment-layout hbuf[t]
    int hcol = p*4 + uj;
    int kth = hcol >> 5, kk = hcol & 31;
    int lane2 = (urow & 15) + ((kk >> 3) << 4);
    int mt2 = urow >> 4;
    size_t idx = (((((size_t)t*8 + mt2)*16 + kth)*64 + lane2)*8) + (kk & 7);
    hbuf[idx] = f2bf(h);
    if (LAYER == 2 && t == T_STEPS-1) aux[urow*512 + hcol] = h;
    __syncthreads();   // drains global stores (vmcnt0) before flag release
    if (tid == 0) __hip_atomic_store(&flags[p], t+1, __ATOMIC_RELEASE, __HIP_MEMORY_SCOPE_AGENT);
  }

  if (LAYER == 1){
    // per-channel BN stats: channel = p*4 + uj, reduce s1,s2 over 128 rows
#pragma unroll
    for (int off = 32; off; off >>= 1){ s1 += __shfl_down(s1, off); s2 += __shfl_down(s2, off); }
    __syncthreads();
    if (lane == 0){ zlds[wv*2] = s1; zlds[wv*2+1] = s2; }
    __syncthreads();
    if (tid < 4){
      float a = zlds[(2*tid)*2]   + zlds[(2*tid+1)*2];
      float b = zlds[(2*tid)*2+1] + zlds[(2*tid+1)*2+1];
      aux[(p*4+tid)*2]   = a;
      aux[(p*4+tid)*2+1] = b;
    }
  }
}

// ---------- BN2 + dense head ----------
__global__ __launch_bounds__(512)
void k_epilogue(const float* __restrict__ h2,
                const float* __restrict__ g2, const float* __restrict__ be2,
                const float* __restrict__ Wd1, const float* __restrict__ bd1,
                const float* __restrict__ Wd2, const float* __restrict__ bd2,
                float* __restrict__ out){
  __shared__ float mu[512], rs[512], bb[512];
  __shared__ float t16[128*16];
  int tid = threadIdx.x;
  {
    float s = 0.f, q = 0.f;
    for (int r = 0; r < 128; r++){ float v = h2[r*512 + tid]; s += v; q += v*v; }
    float m = s * (1.f/128.f);
    float var = q * (1.f/128.f) - m*m;
    mu[tid] = m;
    rs[tid] = rsqrtf(fmaxf(var,0.f) + 1e-5f) * g2[tid];
    bb[tid] = be2[tid];
  }
  __syncthreads();
  for (int task = tid; task < 2048; task += 512){
    int b = task >> 4, u = task & 15;
    float acc = bd1[u];
    for (int k = 0; k < 512; k++){
      float hn = (h2[b*512 + k] - mu[k]) * rs[k] + bb[k];
      acc += hn * Wd1[k*16 + u];
    }
    t16[task] = tanhf(acc);
  }
  __syncthreads();
  if (tid < 128){
    float acc = bd2[0];
#pragma unroll
    for (int u = 0; u < 16; u++) acc += t16[tid*16 + u] * Wd2[u];
    out[tid] = acc;
  }
}

extern "C" void kernel_launch(void* const* d_in, const int* in_sizes, int n_in,
                              void* d_out, int out_size, void* d_ws, size_t ws_size,
                              hipStream_t stream){
  const float* x    = (const float*)d_in[0];
  const float* Wi1  = (const float*)d_in[1];
  const float* Wh1  = (const float*)d_in[2];
  const float* b1   = (const float*)d_in[3];
  const float* Wi2  = (const float*)d_in[4];
  const float* Wh2  = (const float*)d_in[5];
  const float* b2   = (const float*)d_in[6];
  const float* g1   = (const float*)d_in[7];
  const float* be1  = (const float*)d_in[8];
  const float* g2   = (const float*)d_in[9];
  const float* be2  = (const float*)d_in[10];
  const float* Wd1  = (const float*)d_in[11];
  const float* bd1  = (const float*)d_in[12];
  const float* Wd2  = (const float*)d_in[13];
  const float* bd2  = (const float*)d_in[14];
  float* out = (float*)d_out;

  char* ws = (char*)d_ws;
  size_t off = 0;
  auto alloc = [&](size_t bytes)->void*{
    void* pp = ws + off; off += (bytes + 255) & ~(size_t)255; return pp;
  };
  const size_t packed_sz = (size_t)T_STEPS*8*16*64*8*2;   // 64 MiB
  unsigned short* xpacked  = (unsigned short*)alloc(packed_sz); // reused as h2 exchange
  unsigned short* h1packed = (unsigned short*)alloc(packed_sz);
  unsigned short* w1p = (unsigned short*)alloc((size_t)128*32*64*8*2);
  unsigned short* w2p = (unsigned short*)alloc((size_t)128*32*64*8*2);
  float* bias1  = (float*)alloc(2048*4);
  float* bias2  = (float*)alloc(2048*4);
  float* stats1 = (float*)alloc(1024*4);
  int*   flags1 = (int*)alloc(4096);
  int*   flags2 = (int*)alloc(4096);
  float* h2last = (float*)alloc((size_t)128*512*4);

  if (off > ws_size){
    // diagnostic sentinel: report ws_size in MiB via d_out
    k_sentinel<<<1, 256, 0, stream>>>(out, out_size, (float)(ws_size >> 20));
    return;
  }

  k_reset<<<1, 256, 0, stream>>>(flags1, flags2);
  k_pack_x<<<T_STEPS, 256, 0, stream>>>(x, xpacked);
  k_pack_w1<<<NBLK, 256, 0, stream>>>(Wi1, Wh1, b1, w1p, bias1);
  k_scan<1><<<NBLK, 512, 0, stream>>>(xpacked, w1p, bias1, h1packed, flags1, stats1);
  k_fold2<<<NBLK, 256, 0, stream>>>(Wi2, Wh2, b2, g1, be1, stats1, w2p, bias2);
  k_scan<2><<<NBLK, 512, 0, stream>>>(h1packed, w2p, bias2, xpacked, flags2, h2last);
  k_epilogue<<<1, 512, 0, stream>>>(h2last, g2, be2, Wd1, bd1, Wd2, bd2, out);
}